// Round 9
// baseline (322.773 us; speedup 1.0000x reference)
//
#include <hip/hip_runtime.h>

#define N_NODES 100000
#define N_EDGES 1600000
#define F 128
#define NB_SCAN ((N_NODES + 1023) / 1024)   // 98
#define NSUB 32                              // CSR sub-partitions
#define SUB_NODES (N_NODES / NSUB)           // 3125
#define BCAP 128                             // LDS bucket capacity (pairs)
#define PCAP 65536                           // global bucket capacity (pairs)
#define NCHUNK 8                             // chunks per partition (hist/place)
#define NCVT ((N_NODES * F / 8 + 255) / 256) // 6250 blocks for x conversion
#define BUCKET_BLOCKS 512
#define PREP_BLOCKS (NCVT + 257)

typedef short short8 __attribute__((ext_vector_type(8)));   // 8 bf16 (4 VGPR)
typedef float f32x4 __attribute__((ext_vector_type(4)));
typedef int int8v __attribute__((ext_vector_type(8)));
typedef unsigned short ushort_t;
typedef ushort_t ushort8 __attribute__((ext_vector_type(8)));

__device__ __forceinline__ ushort_t f2b(float f) {
    union { float f; unsigned u; } v; v.f = f;
    unsigned r = v.u + 0x7fff + ((v.u >> 16) & 1);   // RNE
    return (ushort_t)(r >> 16);
}

// ---------------- fused CSR-bucket + prep (independent block ranges) ----------

__global__ __launch_bounds__(256) void k_bucket_prep(
        const int* __restrict__ src, const int* __restrict__ dst,
        int2* __restrict__ pairs, int* __restrict__ gcur,
        const float* __restrict__ x, ushort_t* __restrict__ xb,
        const float* __restrict__ W1s, const float* __restrict__ W1n,
        const float* __restrict__ W2s, const float* __restrict__ W2n,
        const float* __restrict__ W3, const float* __restrict__ b2,
        const float* __restrict__ b3,
        ushort_t* __restrict__ wb, float* __restrict__ bc) {
    const int tid = threadIdx.x;

    if (blockIdx.x >= BUCKET_BLOCKS) {               // ---- prep part ----
        const int blk = blockIdx.x - BUCKET_BLOCKS;
        if (blk < NCVT) {
            int i = blk * 256 + tid;
            if (i >= N_NODES * F / 8) return;
            const float4* p = reinterpret_cast<const float4*>(x) + (size_t)i * 2;
            float4 a = p[0], b = p[1];
            ushort8 r;
            r[0] = f2b(a.x); r[1] = f2b(a.y); r[2] = f2b(a.z); r[3] = f2b(a.w);
            r[4] = f2b(b.x); r[5] = f2b(b.y); r[6] = f2b(b.z); r[7] = f2b(b.w);
            *reinterpret_cast<ushort8*>(xb + (size_t)i * 8) = r;
            return;
        }
        const int b = blk - NCVT;
        if (b < 128) {
            int g = b * 256 + tid;
            float v = (g < F * F) ? W1s[g] : W1n[g - F * F];
            wb[g] = f2b(v);
        } else if (b < 256) {
            int g = (b - 128) * 256 + tid;
            int m = g >> 14, rem = g & 16383, i = rem >> 7, j = rem & 127;
            const float* __restrict__ W2 = m ? W2n : W2s;
            float s = 0.f;
#pragma unroll 8
            for (int k = 0; k < F; ++k) s += W3[i * F + k] * W2[k * F + j];
            wb[2 * F * F + g] = f2b(s);
        } else if (tid < F) {
            float s = b3[tid];
#pragma unroll 8
            for (int k = 0; k < F; ++k) s += W3[tid * F + k] * b2[k];
            bc[tid] = s;
        }
        return;
    }

    // ---- bucket part ----
    __shared__ int2 lbuf[NSUB * BCAP];       // 32 KB
    __shared__ int lcnt[NSUB], fbase[NSUB], fcnt[NSUB];
    if (tid < NSUB) lcnt[tid] = 0;
    __syncthreads();

    for (int base = blockIdx.x * 1024; base < N_EDGES; base += BUCKET_BLOCKS * 1024) {
#pragma unroll
        for (int r = 0; r < 4; ++r) {
            int idx = base + r * 256 + tid;
            if (idx < N_EDGES) {
                int d = dst[idx], s = src[idx];
                int p = d / SUB_NODES;               // magic-mul
                int dl = d - p * SUB_NODES;
                int slot = atomicAdd(&lcnt[p], 1);
                if (slot < BCAP) lbuf[p * BCAP + slot] = make_int2(dl, s);
                else {                               // overflow slow path
                    int g = atomicAdd(&gcur[p], 1);
                    pairs[(size_t)p * PCAP + g] = make_int2(dl, s);
                }
            }
        }
        __syncthreads();
        if (tid < NSUB) {
            int c = lcnt[tid]; if (c > BCAP) c = BCAP;
            fcnt[tid] = c;
            fbase[tid] = atomicAdd(&gcur[tid], c);
        }
        __syncthreads();
        for (int p = 0; p < NSUB; ++p) {
            int c = fcnt[p];
            for (int i = tid; i < c; i += 256)
                pairs[(size_t)p * PCAP + fbase[p] + i] = lbuf[p * BCAP + i];
        }
        __syncthreads();
        if (tid < NSUB) lcnt[tid] = 0;
        __syncthreads();
    }
}

// per-chunk histogram: grid NSUB*NCHUNK, LDS hist, coalesced global write
__global__ __launch_bounds__(1024) void k_histc(const int2* __restrict__ pairs,
                                                const int* __restrict__ gcur,
                                                int* __restrict__ hists) {
    __shared__ int hc[SUB_NODES];            // 12.5 KB
    const int p = blockIdx.x / NCHUNK;
    const int c = blockIdx.x % NCHUNK;
    for (int i = threadIdx.x; i < SUB_NODES; i += 1024) hc[i] = 0;
    __syncthreads();
    const int n = gcur[p];
    const int chunk = (n + NCHUNK - 1) / NCHUNK;
    const int lo = c * chunk;
    int hi = lo + chunk; if (hi > n) hi = n;
    const int2* __restrict__ sl = pairs + (size_t)p * PCAP;
    for (int i = lo + threadIdx.x; i < hi; i += 1024) atomicAdd(&hc[sl[i].x], 1);
    __syncthreads();
    int* __restrict__ hout = hists + ((size_t)p * NCHUNK + c) * SUB_NODES;
    for (int i = threadIdx.x; i < SUB_NODES; i += 1024) hout[i] = hc[i];
}

// scan pass 1 — sums the NCHUNK chunk-hists per node, then block-scan
__global__ __launch_bounds__(1024) void k_scan1(const int* __restrict__ hists,
                                                int* __restrict__ tmp,
                                                int* __restrict__ bsum) {
    __shared__ int ws[16];
    const int t = threadIdx.x, lane = t & 63, w = t >> 6;
    const int gid = blockIdx.x * 1024 + t;
    int v = 0;
    if (gid < N_NODES) {
        int p = gid / SUB_NODES, i = gid - p * SUB_NODES;
        const int* __restrict__ hp = hists + (size_t)p * NCHUNK * SUB_NODES + i;
#pragma unroll
        for (int c = 0; c < NCHUNK; ++c) v += hp[c * SUB_NODES];
    }
    int x = v;
#pragma unroll
    for (int off = 1; off < 64; off <<= 1) {
        int y = __shfl_up(x, off, 64);
        if (lane >= off) x += y;
    }
    if (lane == 63) ws[w] = x;
    __syncthreads();
    if (w == 0) {
        int s = (lane < 16) ? ws[lane] : 0;
#pragma unroll
        for (int off = 1; off < 16; off <<= 1) {
            int y = __shfl_up(s, off, 64);
            if (lane >= off) s += y;
        }
        if (lane < 16) ws[lane] = s;
    }
    __syncthreads();
    int base = (w == 0) ? 0 : ws[w - 1];
    int incl = base + x;
    if (gid < N_NODES) tmp[gid] = incl;
    if (t == 1023) bsum[blockIdx.x] = incl;
}

// scan pass 2+3 fused
__global__ __launch_bounds__(256) void k_scan23(const int* __restrict__ tmp,
                                                const int* __restrict__ bsum,
                                                int* __restrict__ row_ptr) {
    __shared__ int excl[NB_SCAN];
    const int t = threadIdx.x;
    if (t < 64) {
        const int lane = t;
        int v0 = (lane < NB_SCAN) ? bsum[lane] : 0;
        int v1 = (64 + lane < NB_SCAN) ? bsum[64 + lane] : 0;
        int x0 = v0;
#pragma unroll
        for (int off = 1; off < 64; off <<= 1) {
            int y = __shfl_up(x0, off, 64);
            if (lane >= off) x0 += y;
        }
        int tot0 = __shfl(x0, 63, 64);
        int x1 = v1;
#pragma unroll
        for (int off = 1; off < 64; off <<= 1) {
            int y = __shfl_up(x1, off, 64);
            if (lane >= off) x1 += y;
        }
        if (lane < NB_SCAN) excl[lane] = x0 - v0;
        if (64 + lane < NB_SCAN) excl[64 + lane] = tot0 + x1 - v1;
    }
    __syncthreads();
    int gid = blockIdx.x * 256 + t;
    if (gid >= N_NODES) return;
    row_ptr[gid + 1] = excl[gid >> 10] + tmp[gid];
    if (gid == 0) row_ptr[0] = 0;
}

// per-chunk placement: LDS cursor = row_ptr + prefix of earlier chunk hists
__global__ __launch_bounds__(1024) void k_place2(const int2* __restrict__ pairs,
                                                 const int* __restrict__ gcur,
                                                 const int* __restrict__ row_ptr,
                                                 const int* __restrict__ hists,
                                                 int* __restrict__ col) {
    __shared__ int cur[SUB_NODES];           // 12.5 KB
    const int p = blockIdx.x / NCHUNK;
    const int c = blockIdx.x % NCHUNK;
    const int* __restrict__ hp = hists + (size_t)p * NCHUNK * SUB_NODES;
    for (int i = threadIdx.x; i < SUB_NODES; i += 1024) {
        int s = row_ptr[p * SUB_NODES + i];
        for (int cc = 0; cc < c; ++cc) s += hp[cc * SUB_NODES + i];
        cur[i] = s;
    }
    __syncthreads();
    const int n = gcur[p];
    const int chunk = (n + NCHUNK - 1) / NCHUNK;
    const int lo = c * chunk;
    int hi = lo + chunk; if (hi > n) hi = n;
    const int2* __restrict__ sl = pairs + (size_t)p * PCAP;
    for (int i = lo + threadIdx.x; i < hi; i += 1024) {
        int2 pr = sl[i];
        int pos = atomicAdd(&cur[pr.x], 1);
        col[pos] = pr.y;
    }
}

// ---------------- mean aggregation: one wave per node ----------------
// Main loop: s_load_dwordx8 pulls 8 col indices into SGPRs (scalar pipe),
// gather uses saddr form (uniform base hb+(s<<8), per-lane voffset loff).
// Per edge: 4 VALU (unpack+acc) + 1 VMEM. Tail (<8) uses per-lane loads.

__global__ __launch_bounds__(256) void k_agg(const ushort_t* __restrict__ h,
                                             const int* __restrict__ row_ptr,
                                             const int* __restrict__ col,
                                             ushort_t* __restrict__ out) {
    int node = (blockIdx.x * blockDim.x + threadIdx.x) >> 6;
    if (node >= N_NODES) return;
    const int lane = threadIdx.x & 63;
    const unsigned loff = (unsigned)lane * 4u;       // lane's dword in 256B row
    const char* __restrict__ hb = reinterpret_cast<const char*>(h);
    const int beg = row_ptr[node], end = row_ptr[node + 1];
    float ax = 0.f, ay = 0.f;

    const int nfull = (end - beg) & ~7;              // edges in full 8-blocks
    const int fend = beg + nfull;
    for (int e = beg; e < fend; e += 8) {
        int eu = __builtin_amdgcn_readfirstlane(e);  // wave-uniform anyway
        int8v c8;
        asm volatile("s_load_dwordx8 %0, %1, 0x0\n\ts_waitcnt lgkmcnt(0)"
                     : "=s"(c8) : "s"(col + eu) : "memory");
#pragma unroll
        for (int u = 0; u < 8; ++u) {
            unsigned s = (unsigned)c8[u];            // SGPR -> uniform base
            unsigned v = *reinterpret_cast<const unsigned*>(
                hb + (((size_t)s << 8) + loff));
            ax += __uint_as_float(v << 16);
            ay += __uint_as_float(v & 0xffff0000u);
        }
    }
    for (int e = fend; e < end; ++e) {               // tail 0..7 edges
        unsigned s = (unsigned)col[e];
        unsigned v = *reinterpret_cast<const unsigned*>(
            hb + (((size_t)s << 8) + loff));
        ax += __uint_as_float(v << 16);
        ay += __uint_as_float(v & 0xffff0000u);
    }

    int deg = end - beg;
    float inv = 1.0f / (float)(deg > 0 ? deg : 1);
    unsigned r = ((unsigned)f2b(ax * inv)) | (((unsigned)f2b(ay * inv)) << 16);
    *reinterpret_cast<unsigned*>(out + ((size_t)node << 7) + lane * 2) = r;
}

// ---------------- MFMA layer: out = A0@W0^T + A1@W1^T + b ----------------

template <bool RELU, bool F32OUT>
__global__ __launch_bounds__(512) void k_layer(
        const ushort_t* __restrict__ A0, const ushort_t* __restrict__ A1,
        const ushort_t* __restrict__ W0, const ushort_t* __restrict__ W1,
        const float* __restrict__ bias, void* __restrict__ outv) {
    const int t = threadIdx.x;
    const int lane = t & 63;
    const int wid = t >> 6;
    const int wr = wid >> 2;          // 0..1
    const int wc = wid & 3;           // 0..3
    const int node0 = blockIdx.x * 128;
    const int arow = lane & 15;
    const int kgrp = lane >> 4;       // k offset = kgrp*8

    f32x4 acc[4][2];
#pragma unroll
    for (int fr = 0; fr < 4; ++fr)
#pragma unroll
        for (int fc = 0; fc < 2; ++fc) acc[fr][fc] = (f32x4)(0.f);

#pragma unroll
    for (int ph = 0; ph < 2; ++ph) {
        const ushort_t* __restrict__ A = ph ? A1 : A0;
        const ushort_t* __restrict__ W = ph ? W1 : W0;

        short8 bfrag[4][2];
#pragma unroll
        for (int ks = 0; ks < 4; ++ks)
#pragma unroll
            for (int fc = 0; fc < 2; ++fc) {
                int c = wc * 32 + fc * 16 + arow;
                bfrag[ks][fc] = *reinterpret_cast<const short8*>(W + c * F + ks * 32 + kgrp * 8);
            }

#pragma unroll
        for (int ks = 0; ks < 4; ++ks) {
            short8 afrag[4];
#pragma unroll
            for (int fr = 0; fr < 4; ++fr) {
                int r = node0 + wr * 64 + fr * 16 + arow;
                if (r > N_NODES - 1) r = N_NODES - 1;
                afrag[fr] = *reinterpret_cast<const short8*>(A + (size_t)r * F + ks * 32 + kgrp * 8);
            }
#pragma unroll
            for (int fr = 0; fr < 4; ++fr)
#pragma unroll
                for (int fc = 0; fc < 2; ++fc)
                    acc[fr][fc] = __builtin_amdgcn_mfma_f32_16x16x32_bf16(
                        afrag[fr], bfrag[ks][fc], acc[fr][fc], 0, 0, 0);
        }
    }

    // epilogue: C/D layout col=lane&15, row=(lane>>4)*4+reg  [m89-verified]
#pragma unroll
    for (int fr = 0; fr < 4; ++fr)
#pragma unroll
        for (int fc = 0; fc < 2; ++fc) {
            int c = wc * 32 + fc * 16 + (lane & 15);
            float bv = bias[c];
#pragma unroll
            for (int r4 = 0; r4 < 4; ++r4) {
                int row = node0 + wr * 64 + fr * 16 + (lane >> 4) * 4 + r4;
                if (row >= N_NODES) continue;
                float v = acc[fr][fc][r4] + bv;
                if (RELU) v = fmaxf(v, 0.f);
                if (F32OUT)
                    reinterpret_cast<float*>(outv)[(size_t)row * F + c] = v;
                else
                    reinterpret_cast<ushort_t*>(outv)[(size_t)row * F + c] = f2b(v);
            }
        }
}

// ---------------- launcher ----------------

extern "C" void kernel_launch(void* const* d_in, const int* in_sizes, int n_in,
                              void* d_out, int out_size, void* d_ws, size_t ws_size,
                              hipStream_t stream) {
    const float* x   = (const float*)d_in[0];
    const int*   src = (const int*)d_in[1];
    const int*   dst = (const int*)d_in[2];
    const float* W1s = (const float*)d_in[3];
    const float* W1n = (const float*)d_in[4];
    const float* b1  = (const float*)d_in[5];
    const float* W2s = (const float*)d_in[6];
    const float* W2n = (const float*)d_in[7];
    const float* b2  = (const float*)d_in[8];
    const float* W3  = (const float*)d_in[9];
    const float* b3  = (const float*)d_in[10];
    float* out = (float*)d_out;

    // workspace layout (~85 MB)
    char* p = (char*)d_ws;
    auto align512 = [](size_t v) { return (v + 511) & ~(size_t)511; };
    int* row_ptr = (int*)p;        p += align512((N_NODES + 1) * sizeof(int));
    int* stmp    = (int*)p;        p += align512((size_t)N_NODES * sizeof(int));
    int* bsum    = (int*)p;        p += align512(256 * sizeof(int));
    int* gcur    = (int*)p;        p += align512(NSUB * sizeof(int));
    int* col     = (int*)p;        p += align512((size_t)N_EDGES * sizeof(int));
    ushort_t* wb = (ushort_t*)p;   p += align512((size_t)4 * F * F * sizeof(ushort_t));
    float* bc    = (float*)p;      p += align512(F * sizeof(float));
    ushort_t* xb = (ushort_t*)p;   p += align512((size_t)N_NODES * F * sizeof(ushort_t));
    ushort_t* aggb = (ushort_t*)p; p += align512((size_t)N_NODES * F * sizeof(ushort_t));
    ushort_t* h1b  = (ushort_t*)p; p += align512((size_t)N_NODES * F * sizeof(ushort_t));
    // pairs (16 MB) aliases aggb (25.6 MB): dead before first k_agg writes aggb
    int2* pairs = (int2*)aggb;
    // hists (3.2 MB) aliases h1b (25.6 MB): dead before k_layer writes h1b
    int* hists = (int*)h1b;

    // CSR build (+ prep fused): bucket/prep -> chunk hist -> scan -> chunk place
    hipMemsetAsync(gcur, 0, NSUB * sizeof(int), stream);
    k_bucket_prep<<<BUCKET_BLOCKS + PREP_BLOCKS, 256, 0, stream>>>(
        src, dst, pairs, gcur, x, xb, W1s, W1n, W2s, W2n, W3, b2, b3, wb, bc);
    k_histc<<<NSUB * NCHUNK, 1024, 0, stream>>>(pairs, gcur, hists);
    k_scan1<<<NB_SCAN, 1024, 0, stream>>>(hists, stmp, bsum);
    k_scan23<<<(N_NODES + 255) / 256, 256, 0, stream>>>(stmp, bsum, row_ptr);
    k_place2<<<NSUB * NCHUNK, 1024, 0, stream>>>(pairs, gcur, row_ptr, hists, col);

    const int agg_grid = (N_NODES + 3) / 4;          // 4 waves/block, 1 node/wave
    const int gemm_grid = (N_NODES + 127) / 128;

    // layer 1: h1 = relu(x@W1s^T + agg(x)@W1n^T + b1)
    k_agg<<<agg_grid, 256, 0, stream>>>(xb, row_ptr, col, aggb);
    k_layer<true, false><<<gemm_grid, 512, 0, stream>>>(
        xb, aggb, wb + 0 * F * F, wb + 1 * F * F, b1, h1b);

    // fused layers 2+3: out = h1@(W3@W2s)^T + agg(h1)@(W3@W2n)^T + (W3@b2 + b3)
    k_agg<<<agg_grid, 256, 0, stream>>>(h1b, row_ptr, col, aggb);
    k_layer<false, true><<<gemm_grid, 512, 0, stream>>>(
        h1b, aggb, wb + 2 * F * F, wb + 3 * F * F, bc, out);
}

// Round 10
// 299.420 us; speedup vs baseline: 1.0780x; 1.0780x over previous
//
#include <hip/hip_runtime.h>

#define N_NODES 100000
#define N_EDGES 1600000
#define F 128
#define NSUB 32                              // CSR sub-partitions
#define SUB_NODES (N_NODES / NSUB)           // 3125
#define BCAP 128                             // LDS bucket capacity (pairs)
#define PCAP 65536                           // global bucket capacity (pairs)
#define NCHUNK 8                             // chunks per partition (hist/place)
#define NCVT ((N_NODES * F / 8 + 255) / 256) // 6250 blocks for x conversion
#define BUCKET_BLOCKS 512
#define PREP_BLOCKS (NCVT + 257)

typedef short short8 __attribute__((ext_vector_type(8)));   // 8 bf16 (4 VGPR)
typedef float f32x4 __attribute__((ext_vector_type(4)));
typedef unsigned short ushort_t;
typedef ushort_t ushort8 __attribute__((ext_vector_type(8)));

__device__ __forceinline__ ushort_t f2b(float f) {
    union { float f; unsigned u; } v; v.f = f;
    unsigned r = v.u + 0x7fff + ((v.u >> 16) & 1);   // RNE
    return (ushort_t)(r >> 16);
}

// ---------------- fused CSR-bucket + prep (independent block ranges) ----------

__global__ __launch_bounds__(256) void k_bucket_prep(
        const int* __restrict__ src, const int* __restrict__ dst,
        int2* __restrict__ pairs, int* __restrict__ gcur,
        const float* __restrict__ x, ushort_t* __restrict__ xb,
        const float* __restrict__ W1s, const float* __restrict__ W1n,
        const float* __restrict__ W2s, const float* __restrict__ W2n,
        const float* __restrict__ W3, const float* __restrict__ b2,
        const float* __restrict__ b3,
        ushort_t* __restrict__ wb, float* __restrict__ bc) {
    const int tid = threadIdx.x;

    if (blockIdx.x >= BUCKET_BLOCKS) {               // ---- prep part ----
        const int blk = blockIdx.x - BUCKET_BLOCKS;
        if (blk < NCVT) {
            int i = blk * 256 + tid;
            if (i >= N_NODES * F / 8) return;
            const float4* p = reinterpret_cast<const float4*>(x) + (size_t)i * 2;
            float4 a = p[0], b = p[1];
            ushort8 r;
            r[0] = f2b(a.x); r[1] = f2b(a.y); r[2] = f2b(a.z); r[3] = f2b(a.w);
            r[4] = f2b(b.x); r[5] = f2b(b.y); r[6] = f2b(b.z); r[7] = f2b(b.w);
            *reinterpret_cast<ushort8*>(xb + (size_t)i * 8) = r;
            return;
        }
        const int b = blk - NCVT;
        if (b < 128) {
            int g = b * 256 + tid;
            float v = (g < F * F) ? W1s[g] : W1n[g - F * F];
            wb[g] = f2b(v);
        } else if (b < 256) {
            int g = (b - 128) * 256 + tid;
            int m = g >> 14, rem = g & 16383, i = rem >> 7, j = rem & 127;
            const float* __restrict__ W2 = m ? W2n : W2s;
            float s = 0.f;
#pragma unroll 8
            for (int k = 0; k < F; ++k) s += W3[i * F + k] * W2[k * F + j];
            wb[2 * F * F + g] = f2b(s);
        } else if (tid < F) {
            float s = b3[tid];
#pragma unroll 8
            for (int k = 0; k < F; ++k) s += W3[tid * F + k] * b2[k];
            bc[tid] = s;
        }
        return;
    }

    // ---- bucket part ----
    __shared__ int2 lbuf[NSUB * BCAP];       // 32 KB
    __shared__ int lcnt[NSUB], fbase[NSUB], fcnt[NSUB];
    if (tid < NSUB) lcnt[tid] = 0;
    __syncthreads();

    for (int base = blockIdx.x * 1024; base < N_EDGES; base += BUCKET_BLOCKS * 1024) {
#pragma unroll
        for (int r = 0; r < 4; ++r) {
            int idx = base + r * 256 + tid;
            if (idx < N_EDGES) {
                int d = dst[idx], s = src[idx];
                int p = d / SUB_NODES;               // magic-mul
                int dl = d - p * SUB_NODES;
                int slot = atomicAdd(&lcnt[p], 1);
                if (slot < BCAP) lbuf[p * BCAP + slot] = make_int2(dl, s);
                else {                               // overflow slow path
                    int g = atomicAdd(&gcur[p], 1);
                    pairs[(size_t)p * PCAP + g] = make_int2(dl, s);
                }
            }
        }
        __syncthreads();
        if (tid < NSUB) {
            int c = lcnt[tid]; if (c > BCAP) c = BCAP;
            fcnt[tid] = c;
            fbase[tid] = atomicAdd(&gcur[tid], c);
        }
        __syncthreads();
        for (int p = 0; p < NSUB; ++p) {
            int c = fcnt[p];
            for (int i = tid; i < c; i += 256)
                pairs[(size_t)p * PCAP + fbase[p] + i] = lbuf[p * BCAP + i];
        }
        __syncthreads();
        if (tid < NSUB) lcnt[tid] = 0;
        __syncthreads();
    }
}

// per-chunk histogram: grid NSUB*NCHUNK, LDS hist, coalesced global write
__global__ __launch_bounds__(1024) void k_histc(const int2* __restrict__ pairs,
                                                const int* __restrict__ gcur,
                                                int* __restrict__ hists) {
    __shared__ int hc[SUB_NODES];            // 12.5 KB
    const int p = blockIdx.x / NCHUNK;
    const int c = blockIdx.x % NCHUNK;
    for (int i = threadIdx.x; i < SUB_NODES; i += 1024) hc[i] = 0;
    __syncthreads();
    const int n = gcur[p];
    const int chunk = (n + NCHUNK - 1) / NCHUNK;
    const int lo = c * chunk;
    int hi = lo + chunk; if (hi > n) hi = n;
    const int2* __restrict__ sl = pairs + (size_t)p * PCAP;
    for (int i = lo + threadIdx.x; i < hi; i += 1024) atomicAdd(&hc[sl[i].x], 1);
    __syncthreads();
    int* __restrict__ hout = hists + ((size_t)p * NCHUNK + c) * SUB_NODES;
    for (int i = threadIdx.x; i < SUB_NODES; i += 1024) hout[i] = hc[i];
}

// fused scan + placement: grid NSUB*NCHUNK. Each block (p,c):
//  pbase = excl-scan(gcur)[p] (wave-redundant), per-node counts from 8 chunk
//  hists, 1024-thread block-scan of 3125 counts in LDS -> cursor starts
//  (+ partial sum of chunks < c); c==0 writes the row_ptr slice; then places
//  its chunk via LDS cursors. Replaces scan1+scan23+place2.
__global__ __launch_bounds__(1024) void k_place3(const int2* __restrict__ pairs,
                                                 const int* __restrict__ gcur,
                                                 const int* __restrict__ hists,
                                                 int* __restrict__ row_ptr,
                                                 int* __restrict__ col) {
    __shared__ int cur[SUB_NODES];           // 12.5 KB
    __shared__ int ws[16];
    const int t = threadIdx.x, lane = t & 63, w = t >> 6;
    const int p = blockIdx.x / NCHUNK;
    const int c = blockIdx.x % NCHUNK;
    const int* __restrict__ hp = hists + (size_t)p * NCHUNK * SUB_NODES;

    // partition base: sum of gcur[q] for q < p (wave-redundant, no sync needed)
    int pv = (lane < p) ? gcur[lane] : 0;    // p <= 31 so lane < p => lane < 32
#pragma unroll
    for (int off = 32; off > 0; off >>= 1) pv += __shfl_xor(pv, off, 64);
    const int pbase = pv;

    // per-thread 4 nodes: full counts + partial (chunks < c)
    int cnt[4], par[4];
#pragma unroll
    for (int j = 0; j < 4; ++j) {
        int i = t * 4 + j;
        int full = 0, part = 0;
        if (i < SUB_NODES) {
#pragma unroll
            for (int cc = 0; cc < NCHUNK; ++cc) {
                int hv = hp[cc * SUB_NODES + i];
                full += hv;
                if (cc < c) part += hv;
            }
        }
        cnt[j] = full; par[j] = part;
    }
    int lsum = cnt[0] + cnt[1] + cnt[2] + cnt[3];

    // block exclusive scan of per-thread sums
    int x = lsum;
#pragma unroll
    for (int off = 1; off < 64; off <<= 1) {
        int y = __shfl_up(x, off, 64);
        if (lane >= off) x += y;
    }
    if (lane == 63) ws[w] = x;
    __syncthreads();
    if (w == 0) {
        int s = (lane < 16) ? ws[lane] : 0;
#pragma unroll
        for (int off = 1; off < 16; off <<= 1) {
            int y = __shfl_up(s, off, 64);
            if (lane >= off) s += y;
        }
        if (lane < 16) ws[lane] = s;
    }
    __syncthreads();
    int run = pbase + ((w == 0) ? 0 : ws[w - 1]) + x - lsum;

#pragma unroll
    for (int j = 0; j < 4; ++j) {
        int i = t * 4 + j;
        if (i < SUB_NODES) {
            cur[i] = run + par[j];
            if (c == 0) row_ptr[p * SUB_NODES + i] = run;
            run += cnt[j];
        }
    }
    if (p == 0 && c == 0 && t == 0) row_ptr[N_NODES] = N_EDGES;
    __syncthreads();

    // place this chunk
    const int n = gcur[p];
    const int chunk = (n + NCHUNK - 1) / NCHUNK;
    const int lo = c * chunk;
    int hi = lo + chunk; if (hi > n) hi = n;
    const int2* __restrict__ sl = pairs + (size_t)p * PCAP;
    for (int i = lo + t; i < hi; i += 1024) {
        int2 pr = sl[i];
        int pos = atomicAdd(&cur[pr.x], 1);
        col[pos] = pr.y;
    }
}

// ---------------- mean aggregation: one wave per node (round-7/8 proven) -----
// 8 gathers in flight (masked 8-deep unroll); 32-bit voffset addressing;
// lean unpack (v<<16 / v&0xffff0000); cndmask masking.

__global__ __launch_bounds__(256) void k_agg(const ushort_t* __restrict__ h,
                                             const int* __restrict__ row_ptr,
                                             const int* __restrict__ col,
                                             ushort_t* __restrict__ out) {
    int node = (blockIdx.x * blockDim.x + threadIdx.x) >> 6;
    if (node >= N_NODES) return;
    const int lane = threadIdx.x & 63;
    const unsigned loff = (unsigned)lane * 4u;       // lane's dword in 256B row
    const char* __restrict__ hb = reinterpret_cast<const char*>(h);
    const int beg = row_ptr[node], end = row_ptr[node + 1];
    float ax = 0.f, ay = 0.f;
    for (int e = beg; e < end; e += 8) {
        unsigned v[8];
#pragma unroll
        for (int u = 0; u < 8; ++u) {
            int idx = e + u; idx = (idx < end) ? idx : end - 1;   // uniform clamp (SALU)
            unsigned s = (unsigned)col[idx];                      // broadcast load
            v[u] = *reinterpret_cast<const unsigned*>(hb + (size_t)((s << 8) + loff));
        }
#pragma unroll
        for (int u = 0; u < 8; ++u) {
            unsigned vv = (e + u < end) ? v[u] : 0u;              // 1 cndmask
            ax += __uint_as_float(vv << 16);
            ay += __uint_as_float(vv & 0xffff0000u);
        }
    }
    int deg = end - beg;
    float inv = 1.0f / (float)(deg > 0 ? deg : 1);
    unsigned r = ((unsigned)f2b(ax * inv)) | (((unsigned)f2b(ay * inv)) << 16);
    *reinterpret_cast<unsigned*>(out + ((size_t)node << 7) + lane * 2) = r;
}

// ---------------- MFMA layer: out = A0@W0^T + A1@W1^T + b ----------------

template <bool RELU, bool F32OUT>
__global__ __launch_bounds__(512) void k_layer(
        const ushort_t* __restrict__ A0, const ushort_t* __restrict__ A1,
        const ushort_t* __restrict__ W0, const ushort_t* __restrict__ W1,
        const float* __restrict__ bias, void* __restrict__ outv) {
    const int t = threadIdx.x;
    const int lane = t & 63;
    const int wid = t >> 6;
    const int wr = wid >> 2;          // 0..1
    const int wc = wid & 3;           // 0..3
    const int node0 = blockIdx.x * 128;
    const int arow = lane & 15;
    const int kgrp = lane >> 4;       // k offset = kgrp*8

    f32x4 acc[4][2];
#pragma unroll
    for (int fr = 0; fr < 4; ++fr)
#pragma unroll
        for (int fc = 0; fc < 2; ++fc) acc[fr][fc] = (f32x4)(0.f);

#pragma unroll
    for (int ph = 0; ph < 2; ++ph) {
        const ushort_t* __restrict__ A = ph ? A1 : A0;
        const ushort_t* __restrict__ W = ph ? W1 : W0;

        short8 bfrag[4][2];
#pragma unroll
        for (int ks = 0; ks < 4; ++ks)
#pragma unroll
            for (int fc = 0; fc < 2; ++fc) {
                int c = wc * 32 + fc * 16 + arow;
                bfrag[ks][fc] = *reinterpret_cast<const short8*>(W + c * F + ks * 32 + kgrp * 8);
            }

#pragma unroll
        for (int ks = 0; ks < 4; ++ks) {
            short8 afrag[4];
#pragma unroll
            for (int fr = 0; fr < 4; ++fr) {
                int r = node0 + wr * 64 + fr * 16 + arow;
                if (r > N_NODES - 1) r = N_NODES - 1;
                afrag[fr] = *reinterpret_cast<const short8*>(A + (size_t)r * F + ks * 32 + kgrp * 8);
            }
#pragma unroll
            for (int fr = 0; fr < 4; ++fr)
#pragma unroll
                for (int fc = 0; fc < 2; ++fc)
                    acc[fr][fc] = __builtin_amdgcn_mfma_f32_16x16x32_bf16(
                        afrag[fr], bfrag[ks][fc], acc[fr][fc], 0, 0, 0);
        }
    }

    // epilogue: C/D layout col=lane&15, row=(lane>>4)*4+reg  [m89-verified]
#pragma unroll
    for (int fr = 0; fr < 4; ++fr)
#pragma unroll
        for (int fc = 0; fc < 2; ++fc) {
            int c = wc * 32 + fc * 16 + (lane & 15);
            float bv = bias[c];
#pragma unroll
            for (int r4 = 0; r4 < 4; ++r4) {
                int row = node0 + wr * 64 + fr * 16 + (lane >> 4) * 4 + r4;
                if (row >= N_NODES) continue;
                float v = acc[fr][fc][r4] + bv;
                if (RELU) v = fmaxf(v, 0.f);
                if (F32OUT)
                    reinterpret_cast<float*>(outv)[(size_t)row * F + c] = v;
                else
                    reinterpret_cast<ushort_t*>(outv)[(size_t)row * F + c] = f2b(v);
            }
        }
}

// ---------------- launcher ----------------

extern "C" void kernel_launch(void* const* d_in, const int* in_sizes, int n_in,
                              void* d_out, int out_size, void* d_ws, size_t ws_size,
                              hipStream_t stream) {
    const float* x   = (const float*)d_in[0];
    const int*   src = (const int*)d_in[1];
    const int*   dst = (const int*)d_in[2];
    const float* W1s = (const float*)d_in[3];
    const float* W1n = (const float*)d_in[4];
    const float* b1  = (const float*)d_in[5];
    const float* W2s = (const float*)d_in[6];
    const float* W2n = (const float*)d_in[7];
    const float* b2  = (const float*)d_in[8];
    const float* W3  = (const float*)d_in[9];
    const float* b3  = (const float*)d_in[10];
    float* out = (float*)d_out;

    // workspace layout (~82 MB)
    char* p = (char*)d_ws;
    auto align512 = [](size_t v) { return (v + 511) & ~(size_t)511; };
    int* row_ptr = (int*)p;        p += align512((N_NODES + 1) * sizeof(int));
    int* gcur    = (int*)p;        p += align512(NSUB * sizeof(int));
    int* col     = (int*)p;        p += align512((size_t)N_EDGES * sizeof(int));
    ushort_t* wb = (ushort_t*)p;   p += align512((size_t)4 * F * F * sizeof(ushort_t));
    float* bc    = (float*)p;      p += align512(F * sizeof(float));
    ushort_t* xb = (ushort_t*)p;   p += align512((size_t)N_NODES * F * sizeof(ushort_t));
    ushort_t* aggb = (ushort_t*)p; p += align512((size_t)N_NODES * F * sizeof(ushort_t));
    ushort_t* h1b  = (ushort_t*)p; p += align512((size_t)N_NODES * F * sizeof(ushort_t));
    // pairs (16 MB) aliases aggb (25.6 MB): dead before first k_agg writes aggb
    int2* pairs = (int2*)aggb;
    // hists (3.2 MB) aliases h1b (25.6 MB): dead before k_layer writes h1b
    int* hists = (int*)h1b;

    // CSR build (+ prep fused): bucket/prep -> chunk hist -> fused scan+place
    hipMemsetAsync(gcur, 0, NSUB * sizeof(int), stream);
    k_bucket_prep<<<BUCKET_BLOCKS + PREP_BLOCKS, 256, 0, stream>>>(
        src, dst, pairs, gcur, x, xb, W1s, W1n, W2s, W2n, W3, b2, b3, wb, bc);
    k_histc<<<NSUB * NCHUNK, 1024, 0, stream>>>(pairs, gcur, hists);
    k_place3<<<NSUB * NCHUNK, 1024, 0, stream>>>(pairs, gcur, hists, row_ptr, col);

    const int agg_grid = (N_NODES + 3) / 4;          // 4 waves/block, 1 node/wave
    const int gemm_grid = (N_NODES + 127) / 128;

    // layer 1: h1 = relu(x@W1s^T + agg(x)@W1n^T + b1)
    k_agg<<<agg_grid, 256, 0, stream>>>(xb, row_ptr, col, aggb);
    k_layer<true, false><<<gemm_grid, 512, 0, stream>>>(
        xb, aggb, wb + 0 * F * F, wb + 1 * F * F, b1, h1b);

    // fused layers 2+3: out = h1@(W3@W2s)^T + agg(h1)@(W3@W2n)^T + (W3@b2 + b3)
    k_agg<<<agg_grid, 256, 0, stream>>>(h1b, row_ptr, col, aggb);
    k_layer<false, true><<<gemm_grid, 512, 0, stream>>>(
        h1b, aggb, wb + 2 * F * F, wb + 3 * F * F, bc, out);
}

// Round 11
// 293.922 us; speedup vs baseline: 1.0982x; 1.0187x over previous
//
#include <hip/hip_runtime.h>

#define N_NODES 100000
#define N_EDGES 1600000
#define F 128
#define NSUB 32                              // CSR sub-partitions
#define SUB_NODES (N_NODES / NSUB)           // 3125
#define BCAP 128                             // LDS bucket capacity (pairs)
#define PCAP 65536                           // global bucket capacity (pairs)
#define NCHUNK 8                             // chunks per partition (hist/place)
#define NCVT ((N_NODES * F / 8 + 255) / 256) // 6250 blocks for x conversion
#define BUCKET_BLOCKS 1024
#define PREP_BLOCKS (NCVT + 257)

typedef short short8 __attribute__((ext_vector_type(8)));   // 8 bf16 (4 VGPR)
typedef float f32x4 __attribute__((ext_vector_type(4)));
typedef unsigned short ushort_t;
typedef ushort_t ushort8 __attribute__((ext_vector_type(8)));

__device__ __forceinline__ ushort_t f2b(float f) {
    union { float f; unsigned u; } v; v.f = f;
    unsigned r = v.u + 0x7fff + ((v.u >> 16) & 1);   // RNE
    return (ushort_t)(r >> 16);
}

// ---------------- fused CSR-bucket + prep (independent block ranges) ----------

__global__ __launch_bounds__(256) void k_bucket_prep(
        const int* __restrict__ src, const int* __restrict__ dst,
        int2* __restrict__ pairs, int* __restrict__ gcur,
        const float* __restrict__ x, ushort_t* __restrict__ xb,
        const float* __restrict__ W1s, const float* __restrict__ W1n,
        const float* __restrict__ W2s, const float* __restrict__ W2n,
        const float* __restrict__ W3, const float* __restrict__ b2,
        const float* __restrict__ b3,
        ushort_t* __restrict__ wb, float* __restrict__ bc) {
    const int tid = threadIdx.x;

    if (blockIdx.x >= BUCKET_BLOCKS) {               // ---- prep part ----
        const int blk = blockIdx.x - BUCKET_BLOCKS;
        if (blk < NCVT) {
            int i = blk * 256 + tid;
            if (i >= N_NODES * F / 8) return;
            const float4* p = reinterpret_cast<const float4*>(x) + (size_t)i * 2;
            float4 a = p[0], b = p[1];
            ushort8 r;
            r[0] = f2b(a.x); r[1] = f2b(a.y); r[2] = f2b(a.z); r[3] = f2b(a.w);
            r[4] = f2b(b.x); r[5] = f2b(b.y); r[6] = f2b(b.z); r[7] = f2b(b.w);
            *reinterpret_cast<ushort8*>(xb + (size_t)i * 8) = r;
            return;
        }
        const int b = blk - NCVT;
        if (b < 128) {
            int g = b * 256 + tid;
            float v = (g < F * F) ? W1s[g] : W1n[g - F * F];
            wb[g] = f2b(v);
        } else if (b < 256) {
            int g = (b - 128) * 256 + tid;
            int m = g >> 14, rem = g & 16383, i = rem >> 7, j = rem & 127;
            const float* __restrict__ W2 = m ? W2n : W2s;
            float s = 0.f;
#pragma unroll 8
            for (int k = 0; k < F; ++k) s += W3[i * F + k] * W2[k * F + j];
            wb[2 * F * F + g] = f2b(s);
        } else if (tid < F) {
            float s = b3[tid];
#pragma unroll 8
            for (int k = 0; k < F; ++k) s += W3[tid * F + k] * b2[k];
            bc[tid] = s;
        }
        return;
    }

    // ---- bucket part ----
    __shared__ int2 lbuf[NSUB * BCAP];       // 32 KB
    __shared__ int lcnt[NSUB], fbase[NSUB], fcnt[NSUB];
    __shared__ int sbase[NSUB + 1];          // flush prefix
    const int lane = tid & 63, w = tid >> 6;
    if (tid < NSUB) lcnt[tid] = 0;
    __syncthreads();

    for (int base = blockIdx.x * 1024; base < N_EDGES; base += BUCKET_BLOCKS * 1024) {
#pragma unroll
        for (int r = 0; r < 4; ++r) {
            int idx = base + r * 256 + tid;
            if (idx < N_EDGES) {
                int d = dst[idx], s = src[idx];
                int p = d / SUB_NODES;               // magic-mul
                int dl = d - p * SUB_NODES;
                int slot = atomicAdd(&lcnt[p], 1);
                if (slot < BCAP) lbuf[p * BCAP + slot] = make_int2(dl, s);
                else {                               // overflow slow path
                    int g = atomicAdd(&gcur[p], 1);
                    pairs[(size_t)p * PCAP + g] = make_int2(dl, s);
                }
            }
        }
        __syncthreads();
        if (tid < NSUB) {
            int c = lcnt[tid]; if (c > BCAP) c = BCAP;
            fcnt[tid] = c;
            fbase[tid] = atomicAdd(&gcur[tid], c);
        }
        __syncthreads();
        // prefix over fcnt (wave 0, lanes 0..31)
        if (w == 0) {
            int c = (lane < NSUB) ? fcnt[lane] : 0;
            int xx = c;
#pragma unroll
            for (int off = 1; off < 32; off <<= 1) {
                int y = __shfl_up(xx, off, 64);
                if (lane >= off) xx += y;
            }
            if (lane < NSUB) sbase[lane + 1] = xx;
            if (lane == 0) sbase[0] = 0;
        }
        __syncthreads();
        // flat flush: all threads copy; bucket found by 5-step binary search
        const int total = sbase[NSUB];
        for (int f = tid; f < total; f += 256) {
            int lo2 = 0, hi2 = NSUB;
            while (hi2 - lo2 > 1) {
                int mid = (lo2 + hi2) >> 1;
                if (sbase[mid] <= f) lo2 = mid; else hi2 = mid;
            }
            int i = f - sbase[lo2];
            pairs[(size_t)lo2 * PCAP + fbase[lo2] + i] = lbuf[lo2 * BCAP + i];
        }
        __syncthreads();
        if (tid < NSUB) lcnt[tid] = 0;
        __syncthreads();
    }
}

// per-chunk histogram: grid NSUB*NCHUNK, LDS hist, coalesced global write
__global__ __launch_bounds__(1024) void k_histc(const int2* __restrict__ pairs,
                                                const int* __restrict__ gcur,
                                                int* __restrict__ hists) {
    __shared__ int hc[SUB_NODES];            // 12.5 KB
    const int p = blockIdx.x / NCHUNK;
    const int c = blockIdx.x % NCHUNK;
    for (int i = threadIdx.x; i < SUB_NODES; i += 1024) hc[i] = 0;
    __syncthreads();
    const int n = gcur[p];
    const int chunk = (n + NCHUNK - 1) / NCHUNK;
    const int lo = c * chunk;
    int hi = lo + chunk; if (hi > n) hi = n;
    const int2* __restrict__ sl = pairs + (size_t)p * PCAP;
    for (int i = lo + threadIdx.x; i < hi; i += 1024) atomicAdd(&hc[sl[i].x], 1);
    __syncthreads();
    int* __restrict__ hout = hists + ((size_t)p * NCHUNK + c) * SUB_NODES;
    for (int i = threadIdx.x; i < SUB_NODES; i += 1024) hout[i] = hc[i];
}

// fused scan + placement: grid NSUB*NCHUNK (round-10 proven)
__global__ __launch_bounds__(1024) void k_place3(const int2* __restrict__ pairs,
                                                 const int* __restrict__ gcur,
                                                 const int* __restrict__ hists,
                                                 int* __restrict__ row_ptr,
                                                 int* __restrict__ col) {
    __shared__ int cur[SUB_NODES];           // 12.5 KB
    __shared__ int ws[16];
    const int t = threadIdx.x, lane = t & 63, w = t >> 6;
    const int p = blockIdx.x / NCHUNK;
    const int c = blockIdx.x % NCHUNK;
    const int* __restrict__ hp = hists + (size_t)p * NCHUNK * SUB_NODES;

    // partition base: sum of gcur[q] for q < p (wave-redundant)
    int pv = (lane < p) ? gcur[lane] : 0;
#pragma unroll
    for (int off = 32; off > 0; off >>= 1) pv += __shfl_xor(pv, off, 64);
    const int pbase = pv;

    int cnt[4], par[4];
#pragma unroll
    for (int j = 0; j < 4; ++j) {
        int i = t * 4 + j;
        int full = 0, part = 0;
        if (i < SUB_NODES) {
#pragma unroll
            for (int cc = 0; cc < NCHUNK; ++cc) {
                int hv = hp[cc * SUB_NODES + i];
                full += hv;
                if (cc < c) part += hv;
            }
        }
        cnt[j] = full; par[j] = part;
    }
    int lsum = cnt[0] + cnt[1] + cnt[2] + cnt[3];

    int x = lsum;
#pragma unroll
    for (int off = 1; off < 64; off <<= 1) {
        int y = __shfl_up(x, off, 64);
        if (lane >= off) x += y;
    }
    if (lane == 63) ws[w] = x;
    __syncthreads();
    if (w == 0) {
        int s = (lane < 16) ? ws[lane] : 0;
#pragma unroll
        for (int off = 1; off < 16; off <<= 1) {
            int y = __shfl_up(s, off, 64);
            if (lane >= off) s += y;
        }
        if (lane < 16) ws[lane] = s;
    }
    __syncthreads();
    int run = pbase + ((w == 0) ? 0 : ws[w - 1]) + x - lsum;

#pragma unroll
    for (int j = 0; j < 4; ++j) {
        int i = t * 4 + j;
        if (i < SUB_NODES) {
            cur[i] = run + par[j];
            if (c == 0) row_ptr[p * SUB_NODES + i] = run;
            run += cnt[j];
        }
    }
    if (p == 0 && c == 0 && t == 0) row_ptr[N_NODES] = N_EDGES;
    __syncthreads();

    const int n = gcur[p];
    const int chunk = (n + NCHUNK - 1) / NCHUNK;
    const int lo = c * chunk;
    int hi = lo + chunk; if (hi > n) hi = n;
    const int2* __restrict__ sl = pairs + (size_t)p * PCAP;
    for (int i = lo + t; i < hi; i += 1024) {
        int2 pr = sl[i];
        int pos = atomicAdd(&cur[pr.x], 1);
        col[pos] = pr.y;
    }
}

// ---------------- mean aggregation: one wave per node (round-7/8 proven) -----

__global__ __launch_bounds__(256) void k_agg(const ushort_t* __restrict__ h,
                                             const int* __restrict__ row_ptr,
                                             const int* __restrict__ col,
                                             ushort_t* __restrict__ out) {
    int node = (blockIdx.x * blockDim.x + threadIdx.x) >> 6;
    if (node >= N_NODES) return;
    const int lane = threadIdx.x & 63;
    const unsigned loff = (unsigned)lane * 4u;       // lane's dword in 256B row
    const char* __restrict__ hb = reinterpret_cast<const char*>(h);
    const int beg = row_ptr[node], end = row_ptr[node + 1];
    float ax = 0.f, ay = 0.f;
    for (int e = beg; e < end; e += 8) {
        unsigned v[8];
#pragma unroll
        for (int u = 0; u < 8; ++u) {
            int idx = e + u; idx = (idx < end) ? idx : end - 1;   // uniform clamp (SALU)
            unsigned s = (unsigned)col[idx];                      // broadcast load
            v[u] = *reinterpret_cast<const unsigned*>(hb + (size_t)((s << 8) + loff));
        }
#pragma unroll
        for (int u = 0; u < 8; ++u) {
            unsigned vv = (e + u < end) ? v[u] : 0u;              // 1 cndmask
            ax += __uint_as_float(vv << 16);
            ay += __uint_as_float(vv & 0xffff0000u);
        }
    }
    int deg = end - beg;
    float inv = 1.0f / (float)(deg > 0 ? deg : 1);
    unsigned r = ((unsigned)f2b(ax * inv)) | (((unsigned)f2b(ay * inv)) << 16);
    *reinterpret_cast<unsigned*>(out + ((size_t)node << 7) + lane * 2) = r;
}

// ---------------- MFMA layer: out = A0@W0^T + A1@W1^T + b ----------------

template <bool RELU, bool F32OUT>
__global__ __launch_bounds__(512) void k_layer(
        const ushort_t* __restrict__ A0, const ushort_t* __restrict__ A1,
        const ushort_t* __restrict__ W0, const ushort_t* __restrict__ W1,
        const float* __restrict__ bias, void* __restrict__ outv) {
    const int t = threadIdx.x;
    const int lane = t & 63;
    const int wid = t >> 6;
    const int wr = wid >> 2;          // 0..1
    const int wc = wid & 3;           // 0..3
    const int node0 = blockIdx.x * 128;
    const int arow = lane & 15;
    const int kgrp = lane >> 4;       // k offset = kgrp*8

    f32x4 acc[4][2];
#pragma unroll
    for (int fr = 0; fr < 4; ++fr)
#pragma unroll
        for (int fc = 0; fc < 2; ++fc) acc[fr][fc] = (f32x4)(0.f);

#pragma unroll
    for (int ph = 0; ph < 2; ++ph) {
        const ushort_t* __restrict__ A = ph ? A1 : A0;
        const ushort_t* __restrict__ W = ph ? W1 : W0;

        short8 bfrag[4][2];
#pragma unroll
        for (int ks = 0; ks < 4; ++ks)
#pragma unroll
            for (int fc = 0; fc < 2; ++fc) {
                int c = wc * 32 + fc * 16 + arow;
                bfrag[ks][fc] = *reinterpret_cast<const short8*>(W + c * F + ks * 32 + kgrp * 8);
            }

#pragma unroll
        for (int ks = 0; ks < 4; ++ks) {
            short8 afrag[4];
#pragma unroll
            for (int fr = 0; fr < 4; ++fr) {
                int r = node0 + wr * 64 + fr * 16 + arow;
                if (r > N_NODES - 1) r = N_NODES - 1;
                afrag[fr] = *reinterpret_cast<const short8*>(A + (size_t)r * F + ks * 32 + kgrp * 8);
            }
#pragma unroll
            for (int fr = 0; fr < 4; ++fr)
#pragma unroll
                for (int fc = 0; fc < 2; ++fc)
                    acc[fr][fc] = __builtin_amdgcn_mfma_f32_16x16x32_bf16(
                        afrag[fr], bfrag[ks][fc], acc[fr][fc], 0, 0, 0);
        }
    }

    // epilogue: C/D layout col=lane&15, row=(lane>>4)*4+reg  [m89-verified]
#pragma unroll
    for (int fr = 0; fr < 4; ++fr)
#pragma unroll
        for (int fc = 0; fc < 2; ++fc) {
            int c = wc * 32 + fc * 16 + (lane & 15);
            float bv = bias[c];
#pragma unroll
            for (int r4 = 0; r4 < 4; ++r4) {
                int row = node0 + wr * 64 + fr * 16 + (lane >> 4) * 4 + r4;
                if (row >= N_NODES) continue;
                float v = acc[fr][fc][r4] + bv;
                if (RELU) v = fmaxf(v, 0.f);
                if (F32OUT)
                    reinterpret_cast<float*>(outv)[(size_t)row * F + c] = v;
                else
                    reinterpret_cast<ushort_t*>(outv)[(size_t)row * F + c] = f2b(v);
            }
        }
}

// ---------------- launcher ----------------

extern "C" void kernel_launch(void* const* d_in, const int* in_sizes, int n_in,
                              void* d_out, int out_size, void* d_ws, size_t ws_size,
                              hipStream_t stream) {
    const float* x   = (const float*)d_in[0];
    const int*   src = (const int*)d_in[1];
    const int*   dst = (const int*)d_in[2];
    const float* W1s = (const float*)d_in[3];
    const float* W1n = (const float*)d_in[4];
    const float* b1  = (const float*)d_in[5];
    const float* W2s = (const float*)d_in[6];
    const float* W2n = (const float*)d_in[7];
    const float* b2  = (const float*)d_in[8];
    const float* W3  = (const float*)d_in[9];
    const float* b3  = (const float*)d_in[10];
    float* out = (float*)d_out;

    // workspace layout (~82 MB)
    char* p = (char*)d_ws;
    auto align512 = [](size_t v) { return (v + 511) & ~(size_t)511; };
    int* row_ptr = (int*)p;        p += align512((N_NODES + 1) * sizeof(int));
    int* gcur    = (int*)p;        p += align512(NSUB * sizeof(int));
    int* col     = (int*)p;        p += align512((size_t)N_EDGES * sizeof(int));
    ushort_t* wb = (ushort_t*)p;   p += align512((size_t)4 * F * F * sizeof(ushort_t));
    float* bc    = (float*)p;      p += align512(F * sizeof(float));
    ushort_t* xb = (ushort_t*)p;   p += align512((size_t)N_NODES * F * sizeof(ushort_t));
    ushort_t* aggb = (ushort_t*)p; p += align512((size_t)N_NODES * F * sizeof(ushort_t));
    ushort_t* h1b  = (ushort_t*)p; p += align512((size_t)N_NODES * F * sizeof(ushort_t));
    // pairs (16 MB) aliases aggb (25.6 MB): dead before first k_agg writes aggb
    int2* pairs = (int2*)aggb;
    // hists (3.2 MB) aliases h1b (25.6 MB): dead before k_layer writes h1b
    int* hists = (int*)h1b;

    // CSR build (+ prep fused): bucket/prep -> chunk hist -> fused scan+place
    hipMemsetAsync(gcur, 0, NSUB * sizeof(int), stream);
    k_bucket_prep<<<BUCKET_BLOCKS + PREP_BLOCKS, 256, 0, stream>>>(
        src, dst, pairs, gcur, x, xb, W1s, W1n, W2s, W2n, W3, b2, b3, wb, bc);
    k_histc<<<NSUB * NCHUNK, 1024, 0, stream>>>(pairs, gcur, hists);
    k_place3<<<NSUB * NCHUNK, 1024, 0, stream>>>(pairs, gcur, hists, row_ptr, col);

    const int agg_grid = (N_NODES + 3) / 4;          // 4 waves/block, 1 node/wave
    const int gemm_grid = (N_NODES + 127) / 128;

    // layer 1: h1 = relu(x@W1s^T + agg(x)@W1n^T + b1)
    k_agg<<<agg_grid, 256, 0, stream>>>(xb, row_ptr, col, aggb);
    k_layer<true, false><<<gemm_grid, 512, 0, stream>>>(
        xb, aggb, wb + 0 * F * F, wb + 1 * F * F, b1, h1b);

    // fused layers 2+3: out = h1@(W3@W2s)^T + agg(h1)@(W3@W2n)^T + (W3@b2 + b3)
    k_agg<<<agg_grid, 256, 0, stream>>>(h1b, row_ptr, col, aggb);
    k_layer<false, true><<<gemm_grid, 512, 0, stream>>>(
        h1b, aggb, wb + 2 * F * F, wb + 3 * F * F, bc, out);
}